// Round 1
// baseline (853.347 us; speedup 1.0000x reference)
//
#include <hip/hip_runtime.h>
#include <math.h>

// Softmax fwd + double-Jacobian-apply, fused single pass.
// s = softmax(mu, axis=1); jvp = s*(g - dot1); out = s*(jvp - dot2)
// dot1 = sum(e*g)/Z ; dot2 = (sum(e^2*g) - dot1*sum(e^2)) / Z^2
//
// V2 vs V1 (836 us total): sigma staged via async global_load_lds (no VGPR
// cost, overlaps max phase), only e kept in regs, launch_bounds(512,8) for
// 4 blocks/CU, nontemporal streaming loads/stores.

constexpr int C_DIM = 8192;
constexpr int BLOCK = 512;
constexpr int V4 = C_DIM / BLOCK / 4;   // 4 float4 per thread
constexpr int NWAVES = BLOCK / 64;      // 8

typedef float f4 __attribute__((ext_vector_type(4)));
typedef __attribute__((address_space(1))) const unsigned int guint;
typedef __attribute__((address_space(3))) unsigned int lint;

__global__ __launch_bounds__(BLOCK, 8) void softmax_djvp_kernel(
    const float* __restrict__ mu, const float* __restrict__ sigma,
    float* __restrict__ s_out, float* __restrict__ so_out) {
  __shared__ float lds_g[C_DIM];     // sigma row, 32 KiB
  __shared__ float red_max[NWAVES];
  __shared__ f4 red_sum[NWAVES];

  const int row = blockIdx.x;
  const long base = (long)row * C_DIM;
  const f4* mu4 = (const f4*)(mu + base);
  f4* s4 = (f4*)(s_out + base);
  f4* o4 = (f4*)(so_out + base);

  const int t = threadIdx.x;
  const int wave = t >> 6;
  const int lane = t & 63;

  // 1) mu -> regs FIRST: the max phase then only waits vmcnt down to the
  //    outstanding DMA count, not on sigma.
  f4 m[V4];
#pragma unroll
  for (int k = 0; k < V4; ++k)
    m[k] = __builtin_nontemporal_load(&mu4[t + BLOCK * k]);

  // 2) sigma -> LDS async DMA (wave-uniform dest + lane*16B; 4 x 1 KiB/wave).
  {
    const float* gsrc = sigma + base + wave * 1024 + lane * 4;
    float* ldst = lds_g + wave * 1024;
#pragma unroll
    for (int j = 0; j < 4; ++j) {
      __builtin_amdgcn_global_load_lds((guint*)(gsrc + j * 256),
                                       (lint*)(ldst + j * 256), 16, 0, 0);
    }
  }

  // 3) row max of mu (overlaps the sigma DMA; barrier below drains it).
  float mx = -INFINITY;
#pragma unroll
  for (int k = 0; k < V4; ++k)
    mx = fmaxf(fmaxf(fmaxf(m[k].x, m[k].y), fmaxf(m[k].z, m[k].w)), mx);
#pragma unroll
  for (int off = 32; off > 0; off >>= 1) mx = fmaxf(mx, __shfl_xor(mx, off, 64));
  if (lane == 0) red_max[wave] = mx;
  __syncthreads();  // full vmcnt drain -> lds_g valid after this
#pragma unroll
  for (int w = 0; w < NWAVES; ++w) mx = fmaxf(mx, red_max[w]);

  // 4) e = exp(mu-mx); accumulate Z, sum(e*g), sum(e^2*g), sum(e^2).
  const f4* g4 = (const f4*)lds_g;
  float z = 0.f, a = 0.f, b = 0.f, c = 0.f;
#pragma unroll
  for (int k = 0; k < V4; ++k) {
    f4 gv = g4[t + BLOCK * k];
    float e0 = __expf(m[k].x - mx), e1 = __expf(m[k].y - mx);
    float e2 = __expf(m[k].z - mx), e3 = __expf(m[k].w - mx);
    m[k].x = e0; m[k].y = e1; m[k].z = e2; m[k].w = e3;  // mu regs now hold e
    z += (e0 + e1) + (e2 + e3);
    a += (e0 * gv.x + e1 * gv.y) + (e2 * gv.z + e3 * gv.w);
    b += (e0 * e0 * gv.x + e1 * e1 * gv.y) + (e2 * e2 * gv.z + e3 * e3 * gv.w);
    c += (e0 * e0 + e1 * e1) + (e2 * e2 + e3 * e3);
  }
#pragma unroll
  for (int off = 32; off > 0; off >>= 1) {
    z += __shfl_xor(z, off, 64);
    a += __shfl_xor(a, off, 64);
    b += __shfl_xor(b, off, 64);
    c += __shfl_xor(c, off, 64);
  }
  if (lane == 0) red_sum[wave] = (f4){z, a, b, c};
  __syncthreads();
  z = 0.f; a = 0.f; b = 0.f; c = 0.f;
#pragma unroll
  for (int w = 0; w < NWAVES; ++w) {
    f4 r = red_sum[w];
    z += r.x; a += r.y; b += r.z; c += r.w;
  }

  const float rZ = 1.0f / z;
  const float dot1 = a * rZ;
  const float dot2 = rZ * rZ * (b - dot1 * c);

  // 5) epilogue: s = e*rZ; out = s*(s*(g - dot1) - dot2); streaming stores.
#pragma unroll
  for (int k = 0; k < V4; ++k) {
    f4 gv = g4[t + BLOCK * k];
    float s0 = m[k].x * rZ, s1 = m[k].y * rZ, s2 = m[k].z * rZ, s3 = m[k].w * rZ;
    f4 sv = {s0, s1, s2, s3};
    f4 ov = {s0 * (s0 * (gv.x - dot1) - dot2),
             s1 * (s1 * (gv.y - dot1) - dot2),
             s2 * (s2 * (gv.z - dot1) - dot2),
             s3 * (s3 * (gv.w - dot1) - dot2)};
    __builtin_nontemporal_store(sv, &s4[t + BLOCK * k]);
    __builtin_nontemporal_store(ov, &o4[t + BLOCK * k]);
  }
}

extern "C" void kernel_launch(void* const* d_in, const int* in_sizes, int n_in,
                              void* d_out, int out_size, void* d_ws, size_t ws_size,
                              hipStream_t stream) {
  const float* mu = (const float*)d_in[0];
  const float* sigma = (const float*)d_in[1];
  float* out = (float*)d_out;
  const long n = (long)in_sizes[0];       // B*C
  const int rows = (int)(n / C_DIM);      // 8192
  float* s_out = out;                     // first output: s
  float* so_out = out + n;                // second output: sigma_out

  softmax_djvp_kernel<<<rows, BLOCK, 0, stream>>>(mu, sigma, s_out, so_out);
}